// Round 10
// baseline (152.073 us; speedup 1.0000x reference)
//
#include <hip/hip_runtime.h>

typedef __attribute__((ext_vector_type(8))) short short8;
typedef __attribute__((ext_vector_type(4))) float f32x4;

__device__ __forceinline__ unsigned short f2bf(float f) {
    union { float f; unsigned int u; } v; v.f = f;
    unsigned int u = v.u;
    unsigned int r = u + 0x7FFFu + ((u >> 16) & 1u);
    return (unsigned short)(r >> 16);
}

// Single kernel: distributed Wm production + device-scope barrier + R9 GEMM.
// Grid 1024 blocks x 512 thr = EXACTLY 4 blocks/CU x 256 CUs co-resident:
// launch_bounds(512,8) caps VGPR at 64 (8 waves/SIMD), LDS 32KB (cap 5/CU),
// waves 32/CU (cap 4/CU). No block retires before the barrier -> dispatcher
// must co-schedule all 1024 -> spin barrier cannot deadlock.
__global__ __launch_bounds__(512, 8) void fused_kernel(
    const float* __restrict__ x, const float* __restrict__ v_w,
    const float* __restrict__ proj_w, const float* __restrict__ proj_b,
    unsigned short* __restrict__ Wm, unsigned int* __restrict__ counter,
    float* __restrict__ out)
{
    const int t = threadIdx.x;
    __shared__ alignas(16) char lds[32768];   // ybuf bf16 16KB | wbuf 16KB | f32 tile reuse

    // ======== phase 0: this block's 64 Wm outputs (e fixed, 64 c's) ========
    // W[e][c] = sum_d proj_w[e][d]*v_w[d][c]; 8 threads/output, 32-MAC partials.
    {
        const int o = t >> 3, p = t & 7;
        const int e = blockIdx.x >> 2;
        const int c = ((blockIdx.x & 3) << 6) | o;
        const float* pw = proj_w + e * 256 + p * 32;
        const float* vv = v_w + (p * 32) * 256 + c;
        float a = 0.f;
#pragma unroll
        for (int d = 0; d < 32; ++d) a = fmaf(pw[d], vv[d * 256], a);
        ((float*)lds)[o * 8 + p] = a;
    }
    __syncthreads();
    if (t < 64) {
        const int e = blockIdx.x >> 2;
        const int c = ((blockIdx.x & 3) << 6) | t;
        const float* r = (const float*)lds + t * 8;
        float s = ((r[0] + r[1]) + (r[2] + r[3])) + ((r[4] + r[5]) + (r[6] + r[7]));
        // pre-swizzled layout (R6/R8/R9-verified):
        const int wn = e >> 6, ni = (e >> 4) & 3, lrow = e & 15;
        const int kk = c >> 5, lkg = (c >> 3) & 3, c8 = c & 7;
        const int lane = lkg * 16 + lrow;
        Wm[((((wn * 8 + kk) * 4 + ni) * 64 + lane) * 8) + c8] = f2bf(s);
    }
    __syncthreads();   // Wm stores drained to L2 (vmcnt0 before barrier) + LDS reads done
    if (t == 0) {
        __threadfence();   // agent release: write back this XCD's L2 to coherent point
        __hip_atomic_fetch_add(counter, 1u, __ATOMIC_RELEASE, __HIP_MEMORY_SCOPE_AGENT);
    }

    // ======== blur phase (R9-verbatim): half-row 32px x 256ch ========
    const int idx   = ((blockIdx.x & 7) << 7) | (blockIdx.x >> 3);  // 1024=8*128, bijective
    const int b     = idx >> 7;
    const int h     = (idx >> 1) & 63;
    const int wbase = (idx & 1) * 32;

    const float A1  = (float)(1.0 / 10.71828182845904523536);                 // 1/(e+8)
    const float A0D = (float)(2.71828182845904523536 / 10.71828182845904523536) - A1; // A0-A1

    {
        const int strip = t >> 5;         // 0..15
        const int c0    = (t & 31) * 8;   // 8-channel chunk
        const int px0   = strip * 2;      // local pixel in [0,32)
        const int gw0   = wbase + px0;    // global pixel column

        const f32x4 z = {0.f, 0.f, 0.f, 0.f};
        f32x4 acc[2][2];
#pragma unroll
        for (int i = 0; i < 2; ++i) { acc[i][0] = z; acc[i][1] = z; }

        for (int r = h - 1; r <= h + 1; ++r) {
            if (r < 0 || r >= 64) continue;
            const bool top = (r == h - 1);
            const float* xr = x + (((size_t)b * 64 + r) * 64) * 256 + c0;

            f32x4 pm0, pm1, pc0, pc1;
            if (gw0 == 0) { pm0 = z; pm1 = z; }
            else {
                pm0 = *(const f32x4*)(xr + (gw0 - 1) * 256);
                pm1 = *(const f32x4*)(xr + (gw0 - 1) * 256 + 4);
            }
            pc0 = *(const f32x4*)(xr + gw0 * 256);
            pc1 = *(const f32x4*)(xr + gw0 * 256 + 4);

#pragma unroll
            for (int i = 0; i < 2; ++i) {
                const int gwn = gw0 + i + 1;
                f32x4 pn0 = z, pn1 = z;
                if (gwn < 64) {
                    pn0 = *(const f32x4*)(xr + gwn * 256);
                    pn1 = *(const f32x4*)(xr + gwn * 256 + 4);
                }
                acc[i][0] += A1 * (pm0 + pc0 + pn0);
                acc[i][1] += A1 * (pm1 + pc1 + pn1);
                if (top) {   // tap k=0 extra weight on x[h-1][w-1]
                    acc[i][0] += A0D * pm0;
                    acc[i][1] += A0D * pm1;
                }
                pm0 = pc0; pm1 = pc1; pc0 = pn0; pc1 = pn1;
            }
        }

        // pack to bf16, write swizzled: byte ^= ((w&7)<<4)
#pragma unroll
        for (int i = 0; i < 2; ++i) {
            const int w = px0 + i;        // local row in [0,32)
            union { short8 v; unsigned short u[8]; } pk;
#pragma unroll
            for (int j = 0; j < 4; ++j) {
                pk.u[j]     = f2bf(acc[i][0][j]);
                pk.u[4 + j] = f2bf(acc[i][1][j]);
            }
            unsigned baddr = ((unsigned)w * 512u + (unsigned)c0 * 2u) ^ (((unsigned)(w & 7)) << 4);
            *reinterpret_cast<short8*>(lds + baddr) = pk.v;
        }
    }
    __syncthreads();   // blur complete

    // ======== device-scope barrier: wait for all 1024 Wm producers ========
    if (t == 0) {
        while (__hip_atomic_load(counter, __ATOMIC_RELAXED, __HIP_MEMORY_SCOPE_AGENT) < 1024u)
            __builtin_amdgcn_s_sleep(4);
        __builtin_amdgcn_fence(__ATOMIC_ACQUIRE, "agent");   // inv L1/L2 -> fresh Wm
    }
    __syncthreads();

    // ======== GEMM (R9-verbatim): 8 waves = 2(mi) x 4(wn), W staged in LDS ========
    const int w    = t >> 6;          // wave 0..7
    const int lane = t & 63;
    const int mi   = w >> 2;          // 0..1  -> 16-px half
    const int wn   = w & 3;           // 0..3  -> 64-e quarter
    const int lrow = lane & 15;
    const int lkg  = lane >> 4;       // 0..3
    const int row  = mi * 16 + lrow;  // local pixel this lane produces

    f32x4 acc2[4];
    {
        const f32x4 z = {0.f, 0.f, 0.f, 0.f};
#pragma unroll
        for (int ni = 0; ni < 4; ++ni) acc2[ni] = z;
    }

    const unsigned abase = (unsigned)row * 512u;
    const unsigned aswz  = ((unsigned)(row & 7)) << 4;

    for (int kk = 0; kk < 8; ++kk) {
        if (kk) __syncthreads();   // prev chunk's B-reads done before overwrite
        // stage W chunk kk: wave w copies groups g = 2w, 2w+1 (1KB each, coalesced)
#pragma unroll
        for (int q = 0; q < 2; ++q) {
            const int g = w * 2 + q;                       // g = wn_s*4 + ni_s
            const unsigned short* src =
                Wm + ((((size_t)(g >> 2) * 8 + kk) * 4 + (g & 3)) * 64 + lane) * 8;
            __builtin_amdgcn_global_load_lds(src, (lds + 16384 + g * 1024), 16, 0, 0);
        }
        __syncthreads();   // staging complete (vmcnt drained before barrier)

        const unsigned abyte = (abase + (unsigned)(kk * 64 + lkg * 16)) ^ aswz;
        short8 a = *reinterpret_cast<const short8*>(lds + abyte);
#pragma unroll
        for (int ni = 0; ni < 4; ++ni) {
            short8 bf = *reinterpret_cast<const short8*>(
                lds + 16384 + ((wn * 4 + ni) * 64 + lane) * 16);
            acc2[ni] = __builtin_amdgcn_mfma_f32_16x16x32_bf16(bf, a, acc2[ni], 0, 0, 0);
        }
    }
    __syncthreads();   // all B/A reads done; lds becomes f32 out-tile [32][256]

    // ======== epilogue (R9-verbatim): f32 LDS transpose -> full-line stores ========
#pragma unroll
    for (int ni = 0; ni < 4; ++ni) {
        const unsigned e0 = (unsigned)(wn * 64 + ni * 16 + lkg * 4);
        unsigned baddr = ((unsigned)row * 1024u + e0 * 4u) ^ (((unsigned)(row & 7)) << 4);
        *reinterpret_cast<f32x4*>(lds + baddr) = acc2[ni];
    }
    __syncthreads();

    const f32x4 bias = *reinterpret_cast<const f32x4*>(proj_b + lane * 4);
    const size_t pxbase = (size_t)idx * 32;
#pragma unroll
    for (int j = 0; j < 4; ++j) {
        const int r = j * 8 + w;    // 8 waves x 4 rows = 32 rows
        unsigned baddr = ((unsigned)r * 1024u + (unsigned)lane * 16u)
                         ^ (((unsigned)(r & 7)) << 4);
        f32x4 v = *reinterpret_cast<const f32x4*>(lds + baddr) + bias;
        __builtin_nontemporal_store(v, reinterpret_cast<f32x4*>(out + (pxbase + r) * 256 + lane * 4));
    }
}

extern "C" void kernel_launch(void* const* d_in, const int* in_sizes, int n_in,
                              void* d_out, int out_size, void* d_ws, size_t ws_size,
                              hipStream_t stream) {
    const float* x      = (const float*)d_in[0];
    const float* v_w    = (const float*)d_in[1];
    const float* proj_w = (const float*)d_in[2];
    const float* proj_b = (const float*)d_in[3];
    float* out = (float*)d_out;

    unsigned short* Wm      = (unsigned short*)d_ws;                    // 128 KB, swizzled
    unsigned int*   counter = (unsigned int*)((char*)d_ws + 131072);

    hipMemsetAsync(counter, 0, 4, stream);   // re-zero barrier counter every replay
    fused_kernel<<<1024, 512, 0, stream>>>(x, v_w, proj_w, proj_b, Wm, counter, out);
}

// Round 11
// 29.410 us; speedup vs baseline: 5.1708x; 5.1708x over previous
//
#include <hip/hip_runtime.h>

typedef __attribute__((ext_vector_type(8))) short short8;
typedef __attribute__((ext_vector_type(4))) float f32x4;

__device__ __forceinline__ unsigned short f2bf(float f) {
    union { float f; unsigned int u; } v; v.f = f;
    unsigned int u = v.u;
    unsigned int r = u + 0x7FFFu + ((u >> 16) & 1u);
    return (unsigned short)(r >> 16);
}

// Kernel A (R6/R8/R9-verified): W = proj_w @ v_w, bf16, PRE-SWIZZLED:
// W[e][c], e=(wn*64+ni*16+lrow), c=(kk*32+lkg*8+c8), lane=lkg*16+lrow
// -> idx = (((wn*8+kk)*4+ni)*64 + lane)*8 + c8.
__global__ __launch_bounds__(1024) void wmat_kernel(
    const float* __restrict__ v_w, const float* __restrict__ proj_w,
    unsigned short* __restrict__ Wm)
{
    __shared__ float red[4][256];
    const int e  = blockIdx.x;
    const int c  = threadIdx.x & 255;
    const int dq = threadIdx.x >> 8;   // 0..3

    const float* pw = proj_w + e * 256 + dq * 64;   // wave-uniform -> s_loads
    const float* vv = v_w + (dq * 64) * 256 + c;

    float acc = 0.f;
#pragma unroll 8
    for (int d = 0; d < 64; ++d)
        acc = fmaf(pw[d], vv[d * 256], acc);

    red[dq][c] = acc;
    __syncthreads();
    if (threadIdx.x < 256) {
        float s = red[0][c] + red[1][c] + red[2][c] + red[3][c];
        const int wn = e >> 6, ni = (e >> 4) & 3, lrow = e & 15;
        const int kk = c >> 5, lkg = (c >> 3) & 3, c8 = c & 7;
        const int lane = lkg * 16 + lrow;
        const int idxo = ((((wn * 8 + kk) * 4 + ni) * 64 + lane) * 8) + c8;
        Wm[idxo] = f2bf(s);
    }
}

// Kernel B: one block per 32-px half-row, 1024 blocks x 512 threads (8 waves),
// 32KB LDS, launch_bounds(512,8) -> 4 blocks/CU = 32 waves/CU.
// Phase 1: blur -> bf16 ybuf (16KB, XOR-swizzled).   [R9 verbatim]
// Phase 2: BARRIER-FREE k-loop: A-frags via conflict-free ds_read_b128,
//          B-frags DIRECT from pre-swizzled global Wm (each load = contiguous
//          1KB per wave, L2-resident). Kernel barriers: 19 -> 4; no vmcnt(0)
//          drain points -- compiler pipelines all 32 B-loads freely.
// Phase 3: f32 LDS transpose -> full-line 1KB row stores.  [R9 verbatim]
__global__ __launch_bounds__(512, 8) void fused_kernel(
    const float* __restrict__ x, const unsigned short* __restrict__ Wm,
    const float* __restrict__ proj_b, float* __restrict__ out)
{
    const int idx   = ((blockIdx.x & 7) << 7) | (blockIdx.x >> 3);  // 1024=8*128, bijective
    const int b     = idx >> 7;
    const int h     = (idx >> 1) & 63;
    const int wbase = (idx & 1) * 32;
    const int t     = threadIdx.x;

    __shared__ alignas(16) char lds[32768];   // [0,16K) ybuf bf16 | f32 out-tile reuses all

    const float A1  = (float)(1.0 / 10.71828182845904523536);                 // 1/(e+8)
    const float A0D = (float)(2.71828182845904523536 / 10.71828182845904523536) - A1; // A0-A1

    // ---------------- blur: 16 strips(2px) x 32 chunks(8ch) = 512 ----------------
    {
        const int strip = t >> 5;         // 0..15
        const int c0    = (t & 31) * 8;   // 8-channel chunk
        const int px0   = strip * 2;      // local pixel in [0,32)
        const int gw0   = wbase + px0;    // global pixel column

        const f32x4 z = {0.f, 0.f, 0.f, 0.f};
        f32x4 acc[2][2];
#pragma unroll
        for (int i = 0; i < 2; ++i) { acc[i][0] = z; acc[i][1] = z; }

        for (int r = h - 1; r <= h + 1; ++r) {
            if (r < 0 || r >= 64) continue;
            const bool top = (r == h - 1);
            const float* xr = x + (((size_t)b * 64 + r) * 64) * 256 + c0;

            f32x4 pm0, pm1, pc0, pc1;
            if (gw0 == 0) { pm0 = z; pm1 = z; }
            else {
                pm0 = *(const f32x4*)(xr + (gw0 - 1) * 256);
                pm1 = *(const f32x4*)(xr + (gw0 - 1) * 256 + 4);
            }
            pc0 = *(const f32x4*)(xr + gw0 * 256);
            pc1 = *(const f32x4*)(xr + gw0 * 256 + 4);

#pragma unroll
            for (int i = 0; i < 2; ++i) {
                const int gwn = gw0 + i + 1;
                f32x4 pn0 = z, pn1 = z;
                if (gwn < 64) {
                    pn0 = *(const f32x4*)(xr + gwn * 256);
                    pn1 = *(const f32x4*)(xr + gwn * 256 + 4);
                }
                acc[i][0] += A1 * (pm0 + pc0 + pn0);
                acc[i][1] += A1 * (pm1 + pc1 + pn1);
                if (top) {   // tap k=0 extra weight on x[h-1][w-1]
                    acc[i][0] += A0D * pm0;
                    acc[i][1] += A0D * pm1;
                }
                pm0 = pc0; pm1 = pc1; pc0 = pn0; pc1 = pn1;
            }
        }

        // pack to bf16, write swizzled: byte ^= ((w&7)<<4)
#pragma unroll
        for (int i = 0; i < 2; ++i) {
            const int w = px0 + i;        // local row in [0,32)
            union { short8 v; unsigned short u[8]; } pk;
#pragma unroll
            for (int j = 0; j < 4; ++j) {
                pk.u[j]     = f2bf(acc[i][0][j]);
                pk.u[4 + j] = f2bf(acc[i][1][j]);
            }
            unsigned baddr = ((unsigned)w * 512u + (unsigned)c0 * 2u) ^ (((unsigned)(w & 7)) << 4);
            *reinterpret_cast<short8*>(lds + baddr) = pk.v;
        }
    }
    __syncthreads();   // blur complete; ylds ready

    // ---------------- GEMM: barrier-free, B direct from global ----------------
    const int w    = t >> 6;          // wave 0..7
    const int lane = t & 63;
    const int mi   = w >> 2;          // 0..1  -> 16-px half
    const int wn   = w & 3;           // 0..3  -> 64-e quarter
    const int lrow = lane & 15;
    const int lkg  = lane >> 4;       // 0..3
    const int row  = mi * 16 + lrow;  // local pixel this lane produces

    f32x4 acc2[4];
    {
        const f32x4 z = {0.f, 0.f, 0.f, 0.f};
#pragma unroll
        for (int ni = 0; ni < 4; ++ni) acc2[ni] = z;
    }

    const unsigned abase = (unsigned)row * 512u;
    const unsigned aswz  = ((unsigned)(row & 7)) << 4;
    // pre-swizzled Wm: element offset = wn*16384 + kk*2048 + ni*512 + lane*8
    const unsigned short* wb = Wm + (wn << 14) + (lane << 3);

#pragma unroll
    for (int kk = 0; kk < 8; ++kk) {
        const unsigned abyte = (abase + (unsigned)(kk * 64 + lkg * 16)) ^ aswz;
        short8 a = *reinterpret_cast<const short8*>(lds + abyte);
#pragma unroll
        for (int ni = 0; ni < 4; ++ni) {
            short8 bf = *reinterpret_cast<const short8*>(wb + (kk << 11) + (ni << 9));
            acc2[ni] = __builtin_amdgcn_mfma_f32_16x16x32_bf16(bf, a, acc2[ni], 0, 0, 0);
        }
    }
    __syncthreads();   // all ylds reads done; lds becomes f32 out-tile [32][256]

    // ---------------- epilogue (R9-verbatim): f32 LDS transpose -> full-line stores ----
    // D layout (verified): lane holds e = wn*64+ni*16+lkg*4+(0..3) for px = row.
#pragma unroll
    for (int ni = 0; ni < 4; ++ni) {
        const unsigned e0 = (unsigned)(wn * 64 + ni * 16 + lkg * 4);
        unsigned baddr = ((unsigned)row * 1024u + e0 * 4u) ^ (((unsigned)(row & 7)) << 4);
        *reinterpret_cast<f32x4*>(lds + baddr) = acc2[ni];
    }
    __syncthreads();

    const f32x4 bias = *reinterpret_cast<const f32x4*>(proj_b + lane * 4);
    const size_t pxbase = (size_t)idx * 32;
#pragma unroll
    for (int j = 0; j < 4; ++j) {
        const int r = j * 8 + w;    // 8 waves x 4 rows = 32 rows
        unsigned baddr = ((unsigned)r * 1024u + (unsigned)lane * 16u)
                         ^ (((unsigned)(r & 7)) << 4);
        f32x4 v = *reinterpret_cast<const f32x4*>(lds + baddr) + bias;
        __builtin_nontemporal_store(v, reinterpret_cast<f32x4*>(out + (pxbase + r) * 256 + lane * 4));
    }
}

extern "C" void kernel_launch(void* const* d_in, const int* in_sizes, int n_in,
                              void* d_out, int out_size, void* d_ws, size_t ws_size,
                              hipStream_t stream) {
    const float* x      = (const float*)d_in[0];
    const float* v_w    = (const float*)d_in[1];
    const float* proj_w = (const float*)d_in[2];
    const float* proj_b = (const float*)d_in[3];
    float* out = (float*)d_out;
    unsigned short* Wm = (unsigned short*)d_ws;   // 65536 bf16 = 128 KB, swizzled

    wmat_kernel<<<256, 1024, 0, stream>>>(v_w, proj_w, Wm);
    fused_kernel<<<1024, 512, 0, stream>>>(x, Wm, proj_b, out);
}